// Round 11
// baseline (117.958 us; speedup 1.0000x reference)
//
#include <hip/hip_runtime.h>

// ConvTranspose3d (2,64,32^3) fp32 -> (2,32,66^3), stride2 pad1 outpad1 dil2 k3.
// Odd-grid MFMA: out[n,co,2dp+1,2hp+1,2wp+1] = bias[co] +
//   sum_{ci,kd,kh,kw} x[n,ci,dp+1-kd,hp+1-kh,wp+1-kw] * w[ci,co,kd,kh,kw]
// R11: single merged prep kernel (w-pack | x->f16 im2col layout | all bias rows),
// conv writes ONLY odd/odd rows, distributed split-K reduction, DMA-first order.

#define DOUT 66
#define PL (DOUT*DOUT)                  // 4356 floats/plane

typedef _Float16 half8 __attribute__((ext_vector_type(8)));
typedef float    floatx16 __attribute__((ext_vector_type(16)));

#define X16_N_F16  2228224              // f16 per n: 32*32*2176
#define ROW_B      4352                 // bytes per (id,ih) row: 8ccg*34iwl*8ci*2
#define ZSLAB_OFF  112640               // 8 KB zeros
#define X16_OFF    131072

// prep grid ranges
#define PB_W    216                     // w-pack blocks
#define PB_X    512                     // x16 blocks
#define PB_BA   579                     // bias-a: full planes (od even + od=65)
#define PB_BB   561                     // bias-b: odd planes, oh even + {65}
#define PREP_GRID (PB_W + PB_X + PB_BA + PB_BB)   // 1868

__global__ void __launch_bounds__(256) prep(
    const float* __restrict__ x, const float* __restrict__ w,
    const float* __restrict__ bias, _Float16* __restrict__ wA,
    _Float16* __restrict__ x16, uint4* __restrict__ zslab,
    float* __restrict__ out)
{
    const int tid = threadIdx.x;
    unsigned b = blockIdx.x;

    if (b < PB_W) {
        // ---- wA[cc 4][tap 27][lane 64][8 f16]; lane=co+32*khalf, j->ci ----
        int o = b * 256 + tid;           // < 55296
        int j = o & 7;
        int tmp = o >> 3;
        int lane = tmp & 63;
        int g = tmp >> 6;                // cc*27 + tap
        int cc = g / 27, tap = g - cc * 27;
        int co = lane & 31, khalf = lane >> 5;
        int ci = cc * 16 + khalf * 8 + j;
        wA[o] = (_Float16)w[ci * 864 + co * 27 + tap];
        return;
    }
    b -= PB_W;
    if (b < PB_X) {
        // ---- x -> x16[n][id][ih][ccg 8][iwl 34][ci8 8]; halo zeroed ----
        const int id = b & 31;
        const int q2 = (b >> 5) & 7;     // 4-ih group
        const int n  = b >> 8;
        const int iw = tid & 31;
        const int cihalf = (tid >> 5) & 1;
        const int ihq = tid >> 6;        // 0..3
        const int ih = q2 * 4 + ihq;

        if (b == 0 && tid < 256) {       // zslab: 512 uint4 = 8 KB
            zslab[2 * tid]     = make_uint4(0, 0, 0, 0);
            zslab[2 * tid + 1] = make_uint4(0, 0, 0, 0);
        }

        const float* xr = x + (size_t)n * 2097152 + (id * 32 + ih) * 32 + iw;
        _Float16* drow = x16 + (size_t)n * X16_N_F16 + (id * 32 + ih) * 2176;
        const int c0 = cihalf * 32;

        float f[32];
        #pragma unroll
        for (int j = 0; j < 32; ++j) f[j] = xr[(size_t)(c0 + j) * 32768];
        #pragma unroll
        for (int k = 0; k < 4; ++k) {
            unsigned pk[4];
            #pragma unroll
            for (int j = 0; j < 4; ++j)
                pk[j] = __builtin_bit_cast(unsigned,
                    __builtin_amdgcn_cvt_pkrtz(f[8 * k + 2 * j], f[8 * k + 2 * j + 1]));
            const int ccg = cihalf * 4 + k;
            *(uint4*)(drow + ccg * 272 + (iw + 1) * 8) =
                make_uint4(pk[0], pk[1], pk[2], pk[3]);
        }
        // halo: 4 ih rows x 8 ccg x {iwl 0, 33} = 64 cells
        if (tid < 64) {
            const int ihq2 = tid >> 4;
            const int rem  = tid & 15;
            const int ccg  = rem >> 1, side = rem & 1;
            _Float16* hz = x16 + (size_t)n * X16_N_F16 +
                (id * 32 + q2 * 4 + ihq2) * 2176 + ccg * 272 + (side ? 264 : 0);
            *(uint4*)hz = make_uint4(0, 0, 0, 0);
        }
        return;
    }
    b -= PB_X;
    if (b < PB_BA) {
        // ---- bias-a: full planes, od even (33) + od=65, float4 ----
        const unsigned base = b * 4096u;
        #pragma unroll
        for (int j = 0; j < 16; ++j) {
            unsigned idx = base + j * 256u + tid;
            if (idx >= 2369952u) continue;           // 2*32*34*1089
            unsigned pl = idx / 1089u;
            unsigned slot = idx - pl * 1089u;
            unsigned e  = pl % 34u;
            unsigned nc = pl / 34u;
            unsigned od = (e < 33u) ? 2u * e : 65u;
            float v = bias[nc & 31u];
            float4* p = (float4*)(out + ((size_t)nc * DOUT + od) * PL);
            p[slot] = make_float4(v, v, v, v);
        }
        return;
    }
    b -= PB_BA;
    {
        // ---- bias-b: odd-od planes, rows oh even (33) + oh=65, float2 ----
        const unsigned base = b * 4096u;             // 561*4096 = 2,297,856 exact
        #pragma unroll
        for (int j = 0; j < 16; ++j) {
            unsigned idx = base + j * 256u + tid;    // < 2048*34*33
            unsigned slot = idx % 33u;
            unsigned t2   = idx / 33u;
            unsigned rr   = t2 % 34u;
            unsigned pln  = t2 / 34u;                // nc*32 + dp
            unsigned oh = (rr < 33u) ? 2u * rr : 65u;
            unsigned od = 2u * (pln & 31u) + 1u;
            unsigned nc = pln >> 5;
            float v = bias[nc & 31u];
            float2* p = (float2*)(out + ((size_t)nc * DOUT + od) * PL + oh * DOUT);
            p[slot] = make_float2(v, v);
        }
    }
}

// ---- conv: DMA-staged MFMA, distributed split-K, odd/odd rows only ----
__global__ void __launch_bounds__(256, 2) convt_mfma(
    const _Float16* __restrict__ x16, const _Float16* __restrict__ wA,
    const _Float16* __restrict__ zslab, const float* __restrict__ bias,
    float* __restrict__ out)
{
    __shared__ __align__(16) unsigned char xlds[78848];   // 18 rows x 4352 B (+pad)

    const int tid  = threadIdx.x;
    const int lane = tid & 63;
    const int wv   = tid >> 6;           // wave = K chunk AND output hp row

    unsigned b = blockIdx.x;             // 512: xcd(3) | dp(5) | hq(1)
    const unsigned xcd = b & 7u;
    const int n   = xcd & 1;
    const int dp  = (b >> 3) & 31;
    const int hq  = b >> 8;
    const int hpg = (int)(((xcd >> 1) << 1) | hq);        // 0..7
    const int hpb = hpg * 4;

    // ---- B: async DMA rows -> LDS linear; invalid rows from zslab (FIRST) ----
    const char* xby = (const char*)(x16 + (size_t)n * X16_N_F16);
    const char* zby = (const char*)zslab;
    for (int m = wv; m < 77; m += 4) {   // 77 wave-instrs x 1024 B
        int c = m * 64 + lane;           // 16B chunk index
        int r = c / 272;
        int q = c - r * 272;
        const char* g;
        if (r < 18) {
            int idl = r / 6, ihl = r - idl * 6;
            int id = dp - 1 + idl, ih = hpb - 1 + ihl;
            bool v = ((unsigned)id < 32u) & ((unsigned)ih < 32u);
            g = v ? (xby + (id * 32 + ih) * ROW_B + q * 16) : (zby + q * 16);
        } else {
            g = zby;
        }
        __builtin_amdgcn_global_load_lds(
            (const __attribute__((address_space(1))) void*)g,
            (__attribute__((address_space(3))) void*)(xlds + m * 1024),
            16, 0, 0);
    }

    // ---- A: 27 uint4 batch load (L2 latency hides under DMA transfer) ----
    uint4 A[27];
    const _Float16* wl = wA + ((size_t)wv * 27 * 64 + lane) * 8;
    #pragma unroll
    for (int t = 0; t < 27; ++t) A[t] = *(const uint4*)(wl + t * 512);

    __syncthreads();

    // ---- K-loop: pure ds_read_b128 + MFMA, 4 independent acc chains ----
    const int wp    = lane & 31;
    const int khalf = lane >> 5;
    const int cbase = (2 * wv + khalf) * 544 + wp * 16;

    floatx16 acc[4] = {{}, {}, {}, {}};
    #pragma unroll
    for (int kd = 0; kd < 3; ++kd)
    #pragma unroll
    for (int kh = 0; kh < 3; ++kh)
    #pragma unroll
    for (int kw = 0; kw < 3; ++kw) {
        const int tap = (kd * 3 + kh) * 3 + kw;
        #pragma unroll
        for (int t = 0; t < 4; ++t) {
            const int row = (2 - kd) * 6 + (t + 2 - kh);
            const uint4* bp = (const uint4*)(xlds + row * ROW_B + cbase + (2 - kw) * 16);
            acc[t] = __builtin_amdgcn_mfma_f32_32x32x16_f16(
                __builtin_bit_cast(half8, A[tap]),
                __builtin_bit_cast(half8, *bp), acc[t], 0, 0, 0);
        }
    }

    // ---- distributed split-K reduction: part[t][wsrc][r][lane] over xlds ----
    __syncthreads();
    float* part = (float*)xlds;
    #pragma unroll
    for (int t = 0; t < 4; ++t) {
        if (t == wv) continue;
        #pragma unroll
        for (int r = 0; r < 16; ++r)
            part[((t * 4 + wv) * 16 + r) * 64 + lane] = acc[t][r];
    }
    __syncthreads();

    float s[16];
    #pragma unroll
    for (int r = 0; r < 16; ++r) s[r] = acc[wv][r];
    #pragma unroll
    for (int w2 = 0; w2 < 4; ++w2) {
        if (w2 == wv) continue;
        #pragma unroll
        for (int r = 0; r < 16; ++r)
            s[r] += part[((wv * 4 + w2) * 16 + r) * 64 + lane];
    }

    // ---- store: ONE full odd/odd row per wave (even ow = bias) ----
    const int od = 2 * dp + 1;
    const int oh = 2 * (hpb + wv) + 1;
    #pragma unroll
    for (int r = 0; r < 16; ++r) {
        const int co = (r & 3) + 8 * (r >> 2) + 4 * khalf;   // verified C/D map
        const float bv = bias[co];
        float2* orow = (float2*)(out +
            ((size_t)(n * 32 + co) * DOUT + od) * PL + oh * DOUT);
        orow[wp] = make_float2(bv, s[r] + bv);
        if (wp == 31) orow[32] = make_float2(bv, bv);
    }
}

extern "C" void kernel_launch(void* const* d_in, const int* in_sizes, int n_in,
                              void* d_out, int out_size, void* d_ws, size_t ws_size,
                              hipStream_t stream) {
    const float* x    = (const float*)d_in[0];
    const float* wgt  = (const float*)d_in[1];
    const float* bias = (const float*)d_in[2];
    float* out = (float*)d_out;
    _Float16* wA    = (_Float16*)d_ws;                    // [0, 110592)
    uint4*    zslab = (uint4*)((char*)d_ws + ZSLAB_OFF);  // 8 KB zeros
    _Float16* x16   = (_Float16*)((char*)d_ws + X16_OFF); // 8.9 MB

    prep<<<PREP_GRID, 256, 0, stream>>>(x, wgt, bias, wA, x16, zslab, out);
    convt_mfma<<<512, 256, 0, stream>>>(x16, wA, (const _Float16*)zslab, bias, out);
}